// Round 20
// baseline (257.357 us; speedup 1.0000x reference)
//
#include <hip/hip_runtime.h>

#define N_NODES 100000
#define N_EDGES 1600000
#define IN_F 128
#define OUT_F 64
#define LN_EPS 1e-5f

#define BSHIFT 6                              // 64 nodes per bucket
#define BNODES 64
#define NB ((N_NODES + BNODES - 1) >> BSHIFT) // 1563

// fixed per-bucket capacity (deterministic input; mean 1024, sigma~32).
#define CAP 2048
#define CH 2048

// GEMM tiling
#define MT 64
#define NGEMM ((N_NODES + MT - 1) / MT)        // 1563 tiles

// kernel-1: 5 blocks/CU residency. Grid 1280 = 5*256; role = bid%5:
// role<2 -> GEMM (512 blocks, 3-4 tiles each), else partition (768 blocks,
// chunk 2084). All blocks use exactly 32768B LDS -> 5/CU; VGPR pinned <=102
// via launch_bounds(256,5) -> 20 waves/CU (was 16). One residency round.
#define K1_BLOCKS 1280
#define K1_GEMM_BLOCKS 512
#define K1_PART_BLOCKS 768
#define K1_THREADS 256
#define K1_PART_CHUNK 2084   // 768*2084 = 1600512 >= N_EDGES

typedef __attribute__((ext_vector_type(8))) short short8;
typedef __attribute__((ext_vector_type(4))) float f32x4;

__device__ __forceinline__ unsigned short f2bf(float f) {
  unsigned int u = __float_as_uint(f);
  unsigned int r = (u + 0x7FFFu + ((u >> 16) & 1u)) >> 16;
  return (unsigned short)r;
}
__device__ __forceinline__ float bf2f(unsigned short h) {
  return __uint_as_float((unsigned int)h << 16);
}

// ===========================================================================
// Kernel 1: interleaved GEMM || partition, 32KB LDS both paths.
//   GEMM: C[100000,128] = x @ [W | res_w^T]; A direct from global (R14/R16-
//         verified math); B^T in PERMUTED LDS layout: short8 chunk index
//         ((kt*4+quad)*128 + n) holds shorts [n][kt*32+quad*8 .. +8) of the
//         old row-major layout -- element-exact, 32768B, conflict-uniform.
//   partition: single-pass staged (rec int2 + bucket ushort + in-place
//         lcnt->lpos), chunk 2084, 27092B LDS.
// ===========================================================================
__global__ __launch_bounds__(K1_THREADS, 5) void gemm_partition(
    const float* __restrict__ x, const float* __restrict__ W,
    const float* __restrict__ res_w, const float* __restrict__ res_b,
    const int* __restrict__ esrc, const int* __restrict__ edst,
    const float* __restrict__ ew, unsigned short* __restrict__ support,
    float* __restrict__ resid, int* __restrict__ gcount,
    int2* __restrict__ part) {
  __shared__ __align__(16) char smem[32768];
  const int tid = threadIdx.x;
  const int bid = blockIdx.x;
  const int grp = bid / 5;
  const int role = bid % 5;           // 0..1 GEMM, 2..4 partition

  if (role < 2) {
    // ------------------------- GEMM path -------------------------
    const int gb = grp * 2 + role;                 // 0..511
    short* bts = (short*)smem;                     // permuted B^T, 32768B

    for (int i = tid; i < 128 * 64; i += K1_THREADS) {   // W[k][n] (k=i>>6,n=i&63)
      const int k = i >> 6, n = i & 63;
      bts[((k >> 3) << 10) + (n << 3) + (k & 7)] = (short)f2bf(W[i]);
    }
    for (int i = tid; i < 64 * 128; i += K1_THREADS) {   // res_w[np][k] -> n=64+np
      const int np = i >> 7, k = i & 127;
      bts[((k >> 3) << 10) + ((64 + np) << 3) + (k & 7)] = (short)f2bf(res_w[i]);
    }
    __syncthreads();  // bts read-only after this; tile loop barrier-free

    const int w = tid >> 6;
    const int lane = tid & 63;
    const int m16 = lane & 15;
    const int quad = lane >> 4;

    float rbv[8];
#pragma unroll
    for (int nt = 0; nt < 8; ++nt)
      rbv[nt] = (nt >= 4) ? res_b[nt * 16 + m16 - 64] : 0.f;

    const float4* xr = (const float4*)x;
    const short8* btp = (const short8*)smem;

    for (int g = gb; g < NGEMM; g += K1_GEMM_BLOCKS) {
      const size_t row0 = (size_t)g * MT;
      const size_t arow = row0 + (size_t)(w * 16 + m16);
      const bool ok = arow < N_NODES;
      const size_t abase = arow * 32 + quad * 2;

      short8 afr[4];
#pragma unroll
      for (int kt = 0; kt < 4; ++kt) {
        float4 u = make_float4(0.f, 0.f, 0.f, 0.f);
        float4 v = make_float4(0.f, 0.f, 0.f, 0.f);
        if (ok) {
          u = xr[abase + kt * 8];
          v = xr[abase + kt * 8 + 1];
        }
        short8 a;
        a[0] = (short)f2bf(u.x); a[1] = (short)f2bf(u.y);
        a[2] = (short)f2bf(u.z); a[3] = (short)f2bf(u.w);
        a[4] = (short)f2bf(v.x); a[5] = (short)f2bf(v.y);
        a[6] = (short)f2bf(v.z); a[7] = (short)f2bf(v.w);
        afr[kt] = a;
      }

#pragma unroll
      for (int nt = 0; nt < 8; ++nt) {
        f32x4 acc = {0.f, 0.f, 0.f, 0.f};
#pragma unroll
        for (int kt = 0; kt < 4; ++kt) {
          const short8 bfr = btp[(((kt << 2) + quad) << 7) + (nt << 4) + m16];
          acc = __builtin_amdgcn_mfma_f32_16x16x32_bf16(afr[kt], bfr, acc, 0, 0, 0);
        }
        const int col = nt * 16 + m16;
#pragma unroll
        for (int r = 0; r < 4; ++r) {
          const size_t row = row0 + w * 16 + quad * 4 + r;
          if (row < N_NODES) {
            if (col < 64) support[row * OUT_F + col] = f2bf(acc[r]);
            else          resid[row * OUT_F + (col - 64)] = acc[r] + rbv[nt];
          }
        }
      }
    }
  } else {
    // ------------- partition path (single-pass, 27KB staged) -------------
    const int pb = grp * 3 + (role - 2);           // 0..767
    int2*   rec = (int2*)smem;                     // [2084] packed records
    unsigned short* sbk = (unsigned short*)(smem + 16672);  // [2084] bucket ids
    int*    lcnt = (int*)(smem + 20840);           // [NB] counts -> bases
    for (int i = tid; i < NB; i += K1_THREADS) lcnt[i] = 0;
    __syncthreads();
    const int beg = pb * K1_PART_CHUNK;
    const int end = min(beg + K1_PART_CHUNK, N_EDGES);
    const int n = end - beg;
    for (int i = tid; i < n; i += K1_THREADS) {
      const int d = edst[beg + i];
      const int s = esrc[beg + i];
      rec[i] = make_int2((s << BSHIFT) | (d & 63), __float_as_int(ew[beg + i]));
      const int b = d >> BSHIFT;
      sbk[i] = (unsigned short)b;
      atomicAdd(&lcnt[b], 1);
    }
    __syncthreads();
    for (int i = tid; i < NB; i += K1_THREADS) {   // in-place count -> base
      const int c = lcnt[i];
      lcnt[i] = c ? atomicAdd(&gcount[i], c) : 0;
    }
    __syncthreads();
    for (int i = tid; i < n; i += K1_THREADS) {
      const int b = sbk[i];
      const int p = atomicAdd(&lcnt[b], 1);
      part[(size_t)b * CAP + p] = rec[i];
    }
  }
}

// ===========================================================================
// Kernel 2: per-bucket LDS counting sort + register accumulate + finalize.
// Verified body; beg/end from the fixed-CAP layout. Unchanged.
// ===========================================================================
__global__ __launch_bounds__(512, 4) void bucket_sort_accum(
    const unsigned short* __restrict__ support, const int2* __restrict__ part,
    const int* __restrict__ gcount, const float* __restrict__ resid,
    const float* __restrict__ bias, const float* __restrict__ gamma,
    const float* __restrict__ beta, float* __restrict__ out) {
  __shared__ int2 estage[CH];
  __shared__ int2 esorted[CH];
  __shared__ int bcnt2[BNODES];
  __shared__ int bseg[BNODES];
  __shared__ int bpos[BNODES];
  const int tid = threadIdx.x;
  const int o = tid & 63;
  const int wid = tid >> 6;
  const int b = blockIdx.x;
  const int cnt = min(gcount[b], CAP);
  const size_t beg = (size_t)b * CAP;
  const size_t end = beg + cnt;

  float acc8[8];
#pragma unroll
  for (int t = 0; t < 8; ++t) acc8[t] = 0.f;

  for (size_t base = beg; base < end; base += CH) {
    const int n = (int)min((size_t)CH, end - base);
    __syncthreads();
    if (tid < BNODES) bcnt2[tid] = 0;
    __syncthreads();

    for (int i = tid; i < n; i += 512) {
      const int2 r = part[base + i];
      estage[i] = r;
      atomicAdd(&bcnt2[r.x & 63], 1);
    }
    __syncthreads();

    if (wid == 0) {
      const int v = bcnt2[o];
      int incl = v;
#pragma unroll
      for (int off = 1; off < 64; off <<= 1) {
        const int u = __shfl_up(incl, off, 64);
        if (o >= off) incl += u;
      }
      bseg[o] = incl - v;
      bpos[o] = incl - v;
    }
    __syncthreads();

    for (int i = tid; i < n; i += 512) {
      const int2 r = estage[i];
      const int p = atomicAdd(&bpos[r.x & 63], 1);
      esorted[p] = r;
    }
    __syncthreads();

#pragma unroll
    for (int t = 0; t < 8; ++t) {
      const int j = wid * 8 + t;
      const int s = bseg[j];
      const int c = bcnt2[j];
      float a = acc8[t];
      int e = 0;
      for (; e + 4 <= c; e += 4) {
        const int2 m0 = esorted[s + e + 0];
        const int2 m1 = esorted[s + e + 1];
        const int2 m2 = esorted[s + e + 2];
        const int2 m3 = esorted[s + e + 3];
        const float v0 = bf2f(support[((size_t)((unsigned)m0.x >> 6) << 6) + o]);
        const float v1 = bf2f(support[((size_t)((unsigned)m1.x >> 6) << 6) + o]);
        const float v2 = bf2f(support[((size_t)((unsigned)m2.x >> 6) << 6) + o]);
        const float v3 = bf2f(support[((size_t)((unsigned)m3.x >> 6) << 6) + o]);
        a = fmaf(v0, __int_as_float(m0.y), a);
        a = fmaf(v1, __int_as_float(m1.y), a);
        a = fmaf(v2, __int_as_float(m2.y), a);
        a = fmaf(v3, __int_as_float(m3.y), a);
      }
      for (; e < c; ++e) {
        const int2 m = esorted[s + e];
        a = fmaf(bf2f(support[((size_t)((unsigned)m.x >> 6) << 6) + o]),
                 __int_as_float(m.y), a);
      }
      acc8[t] = a;
    }
  }

  const float bi = bias[o];
  const float ga = gamma[o];
  const float be = beta[o];
#pragma unroll
  for (int t = 0; t < 8; ++t) {
    const int j = wid * 8 + t;
    const int nid = (b << BSHIFT) + j;
    if (nid < N_NODES) {
      const float v = acc8[t] + bi;
      float s = v, sq = v * v;
#pragma unroll
      for (int off = 32; off > 0; off >>= 1) {
        s += __shfl_xor(s, off, 64);
        sq += __shfl_xor(sq, off, 64);
      }
      const float mu = s * (1.f / 64.f);
      const float var = sq * (1.f / 64.f) - mu * mu;
      const float r = rsqrtf(var + LN_EPS);
      const float nrm = fmaxf((v - mu) * r * ga + be, 0.f);
      out[(size_t)nid * OUT_F + o] = nrm + resid[(size_t)nid * OUT_F + o];
    }
  }
}

// ---------------------------------------------------------------------------
extern "C" void kernel_launch(void* const* d_in, const int* in_sizes, int n_in,
                              void* d_out, int out_size, void* d_ws,
                              size_t ws_size, hipStream_t stream) {
  const float* x      = (const float*)d_in[0];
  const float* weight = (const float*)d_in[1];
  const float* bias   = (const float*)d_in[2];
  const float* gamma  = (const float*)d_in[3];
  const float* beta   = (const float*)d_in[4];
  const float* res_w  = (const float*)d_in[5];
  const float* res_b  = (const float*)d_in[6];
  const float* ew     = (const float*)d_in[7];
  const int*   esrc   = (const int*)d_in[8];
  const int*   edst   = (const int*)d_in[9];
  float* out = (float*)d_out;

  char* ws = (char*)d_ws;
  size_t off = 0;
  auto alloc = [&](size_t bytes) {
    void* p = ws + off;
    off += (bytes + 255) & ~(size_t)255;
    return p;
  };
  unsigned short* support = (unsigned short*)alloc((size_t)N_NODES * OUT_F * 2); // 12.8MB
  float* resid   = (float*)alloc((size_t)N_NODES * OUT_F * sizeof(float));       // 25.6MB
  int2*  part    = (int2*)alloc((size_t)NB * CAP * sizeof(int2));                // 25.6MB
  int*   gcount  = (int*)alloc((size_t)NB * sizeof(int));

  hipMemsetAsync(gcount, 0, (size_t)NB * sizeof(int), stream);

  gemm_partition<<<K1_BLOCKS, K1_THREADS, 0, stream>>>(
      x, weight, res_w, res_b, esrc, edst, ew, support, resid, gcount, part);
  bucket_sort_accum<<<NB, 512, 0, stream>>>(support, part, gcount, resid,
                                            bias, gamma, beta, out);
}

// Round 22
// 209.311 us; speedup vs baseline: 1.2295x; 1.2295x over previous
//
#include <hip/hip_runtime.h>

#define N_NODES 100000
#define N_EDGES 1600000
#define IN_F 128
#define OUT_F 64
#define LN_EPS 1e-5f

#define BSHIFT 6                              // 64 nodes per bucket
#define BNODES 64
#define NB ((N_NODES + BNODES - 1) >> BSHIFT) // 1563

// fixed per-bucket capacity (deterministic input; mean 1024, sigma~32).
#define CAP 2048
#define CH 2048

// GEMM tiling
#define MT 64
#define NGEMM ((N_NODES + MT - 1) / MT)        // 1563 tiles

// kernel-1: grid 1280 = 5*256; role = bid%5: role<2 -> GEMM (512 blocks),
// else partition (768 blocks, chunk 2084). All blocks 32768B LDS.
// NO min-waves pin: R20 showed launch_bounds(256,5) forces VGPR->48 with
// massive spills (FETCH 35->100MB, WRITE 78->130MB, k1 63->108us).
// Unpinned this body compiles to ~96 VGPR (R14) <= 102, so 5 blocks/CU
// can still co-schedule naturally (512/96=5 waves/SIMD, 5x32KB=160KB LDS).
#define K1_BLOCKS 1280
#define K1_GEMM_BLOCKS 512
#define K1_PART_BLOCKS 768
#define K1_THREADS 256
#define K1_PART_CHUNK 2084   // 768*2084 = 1600512 >= N_EDGES

typedef __attribute__((ext_vector_type(8))) short short8;
typedef __attribute__((ext_vector_type(4))) float f32x4;

__device__ __forceinline__ unsigned short f2bf(float f) {
  unsigned int u = __float_as_uint(f);
  unsigned int r = (u + 0x7FFFu + ((u >> 16) & 1u)) >> 16;
  return (unsigned short)r;
}
__device__ __forceinline__ float bf2f(unsigned short h) {
  return __uint_as_float((unsigned int)h << 16);
}

// ===========================================================================
// Kernel 1: interleaved GEMM || partition, 32KB LDS both paths.
//   GEMM: C[100000,128] = x @ [W | res_w^T]; A direct from global (R14/R16-
//         verified math); B^T in PERMUTED LDS layout: short8 chunk index
//         ((kt*4+quad)*128 + n) holds shorts [n][kt*32+quad*8 .. +8) of the
//         old row-major layout -- element-exact, 32768B (verified R20).
//   partition: single-pass staged (rec int2 + bucket ushort + in-place
//         lcnt->lpos), chunk 2084, 27092B LDS (verified R20).
// ===========================================================================
__global__ __launch_bounds__(K1_THREADS) void gemm_partition(
    const float* __restrict__ x, const float* __restrict__ W,
    const float* __restrict__ res_w, const float* __restrict__ res_b,
    const int* __restrict__ esrc, const int* __restrict__ edst,
    const float* __restrict__ ew, unsigned short* __restrict__ support,
    float* __restrict__ resid, int* __restrict__ gcount,
    int2* __restrict__ part) {
  __shared__ __align__(16) char smem[32768];
  const int tid = threadIdx.x;
  const int bid = blockIdx.x;
  const int grp = bid / 5;
  const int role = bid % 5;           // 0..1 GEMM, 2..4 partition

  if (role < 2) {
    // ------------------------- GEMM path -------------------------
    const int gb = grp * 2 + role;                 // 0..511
    short* bts = (short*)smem;                     // permuted B^T, 32768B

    for (int i = tid; i < 128 * 64; i += K1_THREADS) {   // W[k][n] (k=i>>6,n=i&63)
      const int k = i >> 6, n = i & 63;
      bts[((k >> 3) << 10) + (n << 3) + (k & 7)] = (short)f2bf(W[i]);
    }
    for (int i = tid; i < 64 * 128; i += K1_THREADS) {   // res_w[np][k] -> n=64+np
      const int np = i >> 7, k = i & 127;
      bts[((k >> 3) << 10) + ((64 + np) << 3) + (k & 7)] = (short)f2bf(res_w[i]);
    }
    __syncthreads();  // bts read-only after this; tile loop barrier-free

    const int w = tid >> 6;
    const int lane = tid & 63;
    const int m16 = lane & 15;
    const int quad = lane >> 4;

    float rbv[8];
#pragma unroll
    for (int nt = 0; nt < 8; ++nt)
      rbv[nt] = (nt >= 4) ? res_b[nt * 16 + m16 - 64] : 0.f;

    const float4* xr = (const float4*)x;
    const short8* btp = (const short8*)smem;

    for (int g = gb; g < NGEMM; g += K1_GEMM_BLOCKS) {
      const size_t row0 = (size_t)g * MT;
      const size_t arow = row0 + (size_t)(w * 16 + m16);
      const bool ok = arow < N_NODES;
      const size_t abase = arow * 32 + quad * 2;

      short8 afr[4];
#pragma unroll
      for (int kt = 0; kt < 4; ++kt) {
        float4 u = make_float4(0.f, 0.f, 0.f, 0.f);
        float4 v = make_float4(0.f, 0.f, 0.f, 0.f);
        if (ok) {
          u = xr[abase + kt * 8];
          v = xr[abase + kt * 8 + 1];
        }
        short8 a;
        a[0] = (short)f2bf(u.x); a[1] = (short)f2bf(u.y);
        a[2] = (short)f2bf(u.z); a[3] = (short)f2bf(u.w);
        a[4] = (short)f2bf(v.x); a[5] = (short)f2bf(v.y);
        a[6] = (short)f2bf(v.z); a[7] = (short)f2bf(v.w);
        afr[kt] = a;
      }

#pragma unroll
      for (int nt = 0; nt < 8; ++nt) {
        f32x4 acc = {0.f, 0.f, 0.f, 0.f};
#pragma unroll
        for (int kt = 0; kt < 4; ++kt) {
          const short8 bfr = btp[(((kt << 2) + quad) << 7) + (nt << 4) + m16];
          acc = __builtin_amdgcn_mfma_f32_16x16x32_bf16(afr[kt], bfr, acc, 0, 0, 0);
        }
        const int col = nt * 16 + m16;
#pragma unroll
        for (int r = 0; r < 4; ++r) {
          const size_t row = row0 + w * 16 + quad * 4 + r;
          if (row < N_NODES) {
            if (col < 64) support[row * OUT_F + col] = f2bf(acc[r]);
            else          resid[row * OUT_F + (col - 64)] = acc[r] + rbv[nt];
          }
        }
      }
    }
  } else {
    // ------------- partition path (single-pass, 27KB staged) -------------
    const int pb = grp * 3 + (role - 2);           // 0..767
    int2*   rec = (int2*)smem;                     // [2084] packed records
    unsigned short* sbk = (unsigned short*)(smem + 16672);  // [2084] bucket ids
    int*    lcnt = (int*)(smem + 20840);           // [NB] counts -> bases
    for (int i = tid; i < NB; i += K1_THREADS) lcnt[i] = 0;
    __syncthreads();
    const int beg = pb * K1_PART_CHUNK;
    const int end = min(beg + K1_PART_CHUNK, N_EDGES);
    const int n = end - beg;
    for (int i = tid; i < n; i += K1_THREADS) {
      const int d = edst[beg + i];
      const int s = esrc[beg + i];
      rec[i] = make_int2((s << BSHIFT) | (d & 63), __float_as_int(ew[beg + i]));
      const int b = d >> BSHIFT;
      sbk[i] = (unsigned short)b;
      atomicAdd(&lcnt[b], 1);
    }
    __syncthreads();
    for (int i = tid; i < NB; i += K1_THREADS) {   // in-place count -> base
      const int c = lcnt[i];
      lcnt[i] = c ? atomicAdd(&gcount[i], c) : 0;
    }
    __syncthreads();
    for (int i = tid; i < n; i += K1_THREADS) {
      const int b = sbk[i];
      const int p = atomicAdd(&lcnt[b], 1);
      part[(size_t)b * CAP + p] = rec[i];
    }
  }
}

// ===========================================================================
// Kernel 2: per-bucket LDS counting sort + register accumulate + finalize.
// Verified body; beg/end from the fixed-CAP layout. Unchanged.
// ===========================================================================
__global__ __launch_bounds__(512, 4) void bucket_sort_accum(
    const unsigned short* __restrict__ support, const int2* __restrict__ part,
    const int* __restrict__ gcount, const float* __restrict__ resid,
    const float* __restrict__ bias, const float* __restrict__ gamma,
    const float* __restrict__ beta, float* __restrict__ out) {
  __shared__ int2 estage[CH];
  __shared__ int2 esorted[CH];
  __shared__ int bcnt2[BNODES];
  __shared__ int bseg[BNODES];
  __shared__ int bpos[BNODES];
  const int tid = threadIdx.x;
  const int o = tid & 63;
  const int wid = tid >> 6;
  const int b = blockIdx.x;
  const int cnt = min(gcount[b], CAP);
  const size_t beg = (size_t)b * CAP;
  const size_t end = beg + cnt;

  float acc8[8];
#pragma unroll
  for (int t = 0; t < 8; ++t) acc8[t] = 0.f;

  for (size_t base = beg; base < end; base += CH) {
    const int n = (int)min((size_t)CH, end - base);
    __syncthreads();
    if (tid < BNODES) bcnt2[tid] = 0;
    __syncthreads();

    for (int i = tid; i < n; i += 512) {
      const int2 r = part[base + i];
      estage[i] = r;
      atomicAdd(&bcnt2[r.x & 63], 1);
    }
    __syncthreads();

    if (wid == 0) {
      const int v = bcnt2[o];
      int incl = v;
#pragma unroll
      for (int off = 1; off < 64; off <<= 1) {
        const int u = __shfl_up(incl, off, 64);
        if (o >= off) incl += u;
      }
      bseg[o] = incl - v;
      bpos[o] = incl - v;
    }
    __syncthreads();

    for (int i = tid; i < n; i += 512) {
      const int2 r = estage[i];
      const int p = atomicAdd(&bpos[r.x & 63], 1);
      esorted[p] = r;
    }
    __syncthreads();

#pragma unroll
    for (int t = 0; t < 8; ++t) {
      const int j = wid * 8 + t;
      const int s = bseg[j];
      const int c = bcnt2[j];
      float a = acc8[t];
      int e = 0;
      for (; e + 4 <= c; e += 4) {
        const int2 m0 = esorted[s + e + 0];
        const int2 m1 = esorted[s + e + 1];
        const int2 m2 = esorted[s + e + 2];
        const int2 m3 = esorted[s + e + 3];
        const float v0 = bf2f(support[((size_t)((unsigned)m0.x >> 6) << 6) + o]);
        const float v1 = bf2f(support[((size_t)((unsigned)m1.x >> 6) << 6) + o]);
        const float v2 = bf2f(support[((size_t)((unsigned)m2.x >> 6) << 6) + o]);
        const float v3 = bf2f(support[((size_t)((unsigned)m3.x >> 6) << 6) + o]);
        a = fmaf(v0, __int_as_float(m0.y), a);
        a = fmaf(v1, __int_as_float(m1.y), a);
        a = fmaf(v2, __int_as_float(m2.y), a);
        a = fmaf(v3, __int_as_float(m3.y), a);
      }
      for (; e < c; ++e) {
        const int2 m = esorted[s + e];
        a = fmaf(bf2f(support[((size_t)((unsigned)m.x >> 6) << 6) + o]),
                 __int_as_float(m.y), a);
      }
      acc8[t] = a;
    }
  }

  const float bi = bias[o];
  const float ga = gamma[o];
  const float be = beta[o];
#pragma unroll
  for (int t = 0; t < 8; ++t) {
    const int j = wid * 8 + t;
    const int nid = (b << BSHIFT) + j;
    if (nid < N_NODES) {
      const float v = acc8[t] + bi;
      float s = v, sq = v * v;
#pragma unroll
      for (int off = 32; off > 0; off >>= 1) {
        s += __shfl_xor(s, off, 64);
        sq += __shfl_xor(sq, off, 64);
      }
      const float mu = s * (1.f / 64.f);
      const float var = sq * (1.f / 64.f) - mu * mu;
      const float r = rsqrtf(var + LN_EPS);
      const float nrm = fmaxf((v - mu) * r * ga + be, 0.f);
      out[(size_t)nid * OUT_F + o] = nrm + resid[(size_t)nid * OUT_F + o];
    }
  }
}

// ---------------------------------------------------------------------------
extern "C" void kernel_launch(void* const* d_in, const int* in_sizes, int n_in,
                              void* d_out, int out_size, void* d_ws,
                              size_t ws_size, hipStream_t stream) {
  const float* x      = (const float*)d_in[0];
  const float* weight = (const float*)d_in[1];
  const float* bias   = (const float*)d_in[2];
  const float* gamma  = (const float*)d_in[3];
  const float* beta   = (const float*)d_in[4];
  const float* res_w  = (const float*)d_in[5];
  const float* res_b  = (const float*)d_in[6];
  const float* ew     = (const float*)d_in[7];
  const int*   esrc   = (const int*)d_in[8];
  const int*   edst   = (const int*)d_in[9];
  float* out = (float*)d_out;

  char* ws = (char*)d_ws;
  size_t off = 0;
  auto alloc = [&](size_t bytes) {
    void* p = ws + off;
    off += (bytes + 255) & ~(size_t)255;
    return p;
  };
  unsigned short* support = (unsigned short*)alloc((size_t)N_NODES * OUT_F * 2); // 12.8MB
  float* resid   = (float*)alloc((size_t)N_NODES * OUT_F * sizeof(float));       // 25.6MB
  int2*  part    = (int2*)alloc((size_t)NB * CAP * sizeof(int2));                // 25.6MB
  int*   gcount  = (int*)alloc((size_t)NB * sizeof(int));

  hipMemsetAsync(gcount, 0, (size_t)NB * sizeof(int), stream);

  gemm_partition<<<K1_BLOCKS, K1_THREADS, 0, stream>>>(
      x, weight, res_w, res_b, esrc, edst, ew, support, resid, gcount, part);
  bucket_sort_accum<<<NB, 512, 0, stream>>>(support, part, gcount, resid,
                                            bias, gamma, beta, out);
}